// Round 4
// baseline (757.991 us; speedup 1.0000x reference)
//
#include <hip/hip_runtime.h>

#define NN 100000
#define NE 2400000
#define NB 391              // buckets of 256 dst nodes
#define P  7                // src chunks (src>>14, max 99999>>14 = 6)
#define NBIN 2737           // NB*P
#define NBINP 3072          // padded (512*6)

// ---------------- zero bin counters ----------------
__global__ void k_zero(int* __restrict__ c) {
    int i = blockIdx.x * 256 + threadIdx.x;
    if (i < NBINP) c[i] = 0;
}

// ---------------- histogram over (dstBucket, srcChunk) bins ----------------
__global__ __launch_bounds__(512) void k_hist(const int* __restrict__ ei,
                                              int* __restrict__ cnt) {
    __shared__ int hist[NBINP];
    int tid = threadIdx.x;
    for (int i = tid; i < NBINP; i += 512) hist[i] = 0;
    __syncthreads();
    int e0 = blockIdx.x * 4096;
    for (int k = 0; k < 8; ++k) {
        int e = e0 + k * 512 + tid;
        if (e < NE) {
            int s = ei[e], d = ei[NE + e];
            atomicAdd(&hist[(d >> 8) * P + (s >> 14)], 1);
        }
    }
    __syncthreads();
    for (int i = tid; i < NBIN; i += 512)
        if (hist[i]) atomicAdd(&cnt[i], hist[i]);
}

// ---------------- exclusive scan over bins (1 block) ----------------
__global__ __launch_bounds__(512) void k_scan(const int* __restrict__ cnt,
        int* __restrict__ base, int* __restrict__ cur) {
    __shared__ int sh[512];
    int tid = threadIdx.x;
    int loc[6]; int s = 0; int b6 = tid * 6;
    for (int j = 0; j < 6; ++j) { int v = cnt[b6 + j]; loc[j] = s; s += v; }
    sh[tid] = s; __syncthreads();
    for (int off = 1; off < 512; off <<= 1) {
        int t = (tid >= off) ? sh[tid - off] : 0; __syncthreads();
        sh[tid] += t; __syncthreads();
    }
    int excl = sh[tid] - s;
    for (int j = 0; j < 6; ++j) {
        int v = excl + loc[j];
        base[b6 + j] = v;          // bins >= NBIN are zero-count: base==NE there
        cur[b6 + j] = v;
    }
}

// ---------------- bin edges by (bucket,srcchunk), LDS-grouped writes ----------------
__global__ __launch_bounds__(512) void k_binscatter(const int* __restrict__ ei,
        int* __restrict__ cur, int* __restrict__ binned) {
    __shared__ int hist[NBINP], lbase[NBINP], myb[NBINP];
    __shared__ int sh[512];
    __shared__ int stage[4096];
    __shared__ unsigned short stageb[4096];
    int tid = threadIdx.x;
    for (int i = tid; i < NBINP; i += 512) hist[i] = 0;
    __syncthreads();
    int e0 = blockIdx.x * 4096;
    int pk[8], bn[8];
    for (int k = 0; k < 8; ++k) {
        int e = e0 + k * 512 + tid;
        if (e < NE) {
            int s = ei[e], d = ei[NE + e];
            bn[k] = (d >> 8) * P + (s >> 14);
            pk[k] = s | ((d & 255) << 17);
            atomicAdd(&hist[bn[k]], 1);
        } else bn[k] = -1;
    }
    __syncthreads();
    // scan hist (6 bins/thread)
    int loc[6]; int s = 0; int b6 = tid * 6;
    for (int j = 0; j < 6; ++j) { int v = hist[b6 + j]; loc[j] = s; s += v; }
    sh[tid] = s; __syncthreads();
    for (int off = 1; off < 512; off <<= 1) {
        int t = (tid >= off) ? sh[tid - off] : 0; __syncthreads();
        sh[tid] += t; __syncthreads();
    }
    int excl = sh[tid] - s;
    int T = sh[511];
    for (int j = 0; j < 6; ++j) lbase[b6 + j] = excl + loc[j];
    __syncthreads();
    // claim global space per touched bin
    for (int i = tid; i < NBIN; i += 512) {
        int v = hist[i];
        if (v > 0) myb[i] = atomicAdd(&cur[i], v);
    }
    __syncthreads();
    // reuse hist as rank counters
    for (int i = tid; i < NBINP; i += 512) hist[i] = 0;
    __syncthreads();
    for (int k = 0; k < 8; ++k) {
        if (bn[k] >= 0) {
            int r = atomicAdd(&hist[bn[k]], 1);
            int slot = lbase[bn[k]] + r;
            stage[slot] = pk[k];
            stageb[slot] = (unsigned short)bn[k];
        }
    }
    __syncthreads();
    for (int j = tid; j < T; j += 512) {
        int b = stageb[j];
        binned[myb[b] + (j - lbase[b])] = stage[j];
    }
}

// ---------------- per-node degree -> dinv ----------------
__global__ __launch_bounds__(256) void k_degrees(const int* __restrict__ binned,
        const int* __restrict__ base, float* __restrict__ dinv) {
    __shared__ int cnt[256];
    int tid = threadIdx.x, b = blockIdx.x;
    cnt[tid] = 0; __syncthreads();
    int beg = base[b * P], end = base[b * P + P];
    for (int e = beg + tid; e < end; e += 256)
        atomicAdd(&cnt[(binned[e] >> 17) & 255], 1);
    __syncthreads();
    int node = (b << 8) + tid;
    if (node < NN) dinv[node] = rsqrtf((float)(cnt[tid] + 1));
}

// ---------------- prescale x by dinv ----------------
__global__ void k_prescale(const float* __restrict__ x, const float* __restrict__ dinv,
                           float2* __restrict__ xs) {
    int i = blockIdx.x * 256 + threadIdx.x;
    if (i < NN) {
        float2 v = ((const float2*)x)[i];
        float di = dinv[i];
        xs[i] = make_float2(di * v.x, di * v.y);
    }
}

// ---------------- layer 1: edge-parallel 2-wide gather + W1 epilogue ----------------
// writes Y prescaled by dinv[node]
__global__ __launch_bounds__(1024) void k_gl1(const float2* __restrict__ xs,
        const int* __restrict__ binned, const int* __restrict__ base,
        const float* __restrict__ dinv, const float* __restrict__ W,
        const float* __restrict__ bias, float* __restrict__ Y) {
    __shared__ float acc[512];
    __shared__ float ldv[256];
    int tid = threadIdx.x, b = blockIdx.x, node0 = b << 8;
    if (tid < 512) acc[tid] = 0.f;
    if (tid < 256) { int n = node0 + tid; ldv[tid] = (n < NN) ? dinv[n] : 0.f; }
    __syncthreads();
    int beg = base[b * P], end = base[b * P + P];
    for (int e = beg + tid; e < end; e += 1024) {
        int w = binned[e];
        int s = w & 0x1FFFF;
        int dl = (w >> 17) & 255;
        float2 xv = xs[s];                 // already dinv[s]-scaled
        float nd = ldv[dl];
        atomicAdd(&acc[dl * 2],     nd * xv.x);
        atomicAdd(&acc[dl * 2 + 1], nd * xv.y);
    }
    __syncthreads();
    for (int i = tid; i < 8192; i += 1024) {
        int n = i >> 5, f = i & 31, node = node0 + n;
        if (node < NN) {
            float di = ldv[n];
            float2 xo = xs[node];          // di * x[node]
            float a0 = acc[n * 2]     + di * xo.x;   // di^2 * x
            float a1 = acc[n * 2 + 1] + di * xo.y;
            float v = a0 * W[f] + a1 * W[32 + f] + bias[f];
            Y[(node << 5) + f] = di * (v > 0.f ? v : 0.f);   // prescaled output
        }
    }
}

// ---------------- layer 2: edge-parallel 32-wide gather + W2 epilogue ----------------
// H is prescaled; writes O prescaled
__global__ __launch_bounds__(1024) void k_gl2(const float* __restrict__ H,
        const int* __restrict__ binned, const int* __restrict__ base,
        const float* __restrict__ dinv, const float* __restrict__ W,
        const float* __restrict__ bias, float* __restrict__ O) {
    __shared__ float acc[8192];   // 256 x 32
    __shared__ float ldv[256];
    __shared__ float Ws[1024];
    int tid = threadIdx.x, b = blockIdx.x, node0 = b << 8;
    for (int i = tid; i < 8192; i += 1024) acc[i] = 0.f;
    Ws[tid] = W[tid];
    if (tid < 256) { int n = node0 + tid; ldv[tid] = (n < NN) ? dinv[n] : 0.f; }
    __syncthreads();
    int slot = tid >> 5, f = tid & 31;
    int beg = base[b * P], end = base[b * P + P];    // edges sorted by src-chunk
    for (int e = beg + slot; e < end; e += 32) {
        int w = binned[e];
        int s = w & 0x1FFFF;
        int dl = (w >> 17) & 255;
        float v = H[(s << 5) + f];                   // dinv[s]*h1[s][f]
        atomicAdd(&acc[(dl << 5) + f], ldv[dl] * v);
    }
    __syncthreads();
    // self-loop: acc += di * H[node] (= di^2 * h1[node])
    for (int n = slot; n < 256; n += 32) {
        int node = node0 + n;
        if (node < NN) acc[(n << 5) + f] += ldv[n] * H[(node << 5) + f];
    }
    __syncthreads();
    // epilogue: O = di * relu(acc @ W2 + b2)
    for (int n = slot; n < 256; n += 32) {
        int node = node0 + n;
        if (node < NN) {
            float sum = 0.f;
#pragma unroll
            for (int k = 0; k < 32; ++k) sum += acc[(n << 5) + k] * Ws[(k << 5) + f];
            float v = sum + bias[f];
            O[(node << 5) + f] = ldv[n] * (v > 0.f ? v : 0.f);
        }
    }
}

// ---------------- layer 3 transform: h3 = X(prescaled) @ W3 ----------------
__global__ void k_l3t(const float* __restrict__ in, const float* __restrict__ W,
                      float* __restrict__ h) {
    int i = blockIdx.x * 256 + threadIdx.x;
    if (i >= NN) return;
    const float4* row = (const float4*)(in + i * 32);
    const float4* w4 = (const float4*)W;
    float v = 0.f;
#pragma unroll
    for (int k = 0; k < 8; ++k) {
        float4 r = row[k], w = w4[k];
        v += r.x * w.x + r.y * w.y + r.z * w.z + r.w * w.w;
    }
    h[i] = v;    // = dinv[i] * (H2 @ W3)[i]
}

// ---------------- layer 3: edge-parallel 1-wide gather -> out ----------------
__global__ __launch_bounds__(1024) void k_gl3(const float* __restrict__ h3,
        const int* __restrict__ binned, const int* __restrict__ base,
        const float* __restrict__ dinv, const float* __restrict__ bias,
        float* __restrict__ out) {
    __shared__ float acc[256];
    __shared__ float ldv[256];
    int tid = threadIdx.x, b = blockIdx.x, node0 = b << 8;
    if (tid < 256) {
        acc[tid] = 0.f;
        int n = node0 + tid;
        ldv[tid] = (n < NN) ? dinv[n] : 0.f;
    }
    __syncthreads();
    int beg = base[b * P], end = base[b * P + P];
    for (int e = beg + tid; e < end; e += 1024) {
        int w = binned[e];
        int s = w & 0x1FFFF;
        int dl = (w >> 17) & 255;
        atomicAdd(&acc[dl], ldv[dl] * h3[s]);
    }
    __syncthreads();
    if (tid < 256) {
        int node = node0 + tid;
        if (node < NN) {
            float di = ldv[tid];
            out[node] = acc[tid] + di * h3[node] + bias[0];
        }
    }
}

extern "C" void kernel_launch(void* const* d_in, const int* in_sizes, int n_in,
                              void* d_out, int out_size, void* d_ws, size_t ws_size,
                              hipStream_t stream) {
    const float* x  = (const float*)d_in[0];
    const int*   ei = (const int*)d_in[1];   // [2, NE] int32
    const float* W1 = (const float*)d_in[2];
    const float* b1 = (const float*)d_in[3];
    const float* W2 = (const float*)d_in[4];
    const float* b2 = (const float*)d_in[5];
    const float* W3 = (const float*)d_in[6];
    const float* b3 = (const float*)d_in[7];
    float* out = (float*)d_out;

    char* w = (char*)d_ws;
    int*    cnt    = (int*)w;    w += NBINP * 4;
    int*    base   = (int*)w;    w += (NBINP + 1) * 4;
    int*    cur    = (int*)w;    w += NBINP * 4;
    float*  dinv   = (float*)w;  w += NN * 4;
    float2* xs     = (float2*)w; w += NN * 8;
    int*    binned = (int*)w;    w += NE * 4;
    float*  Y      = (float*)w;  w += NN * 32 * 4;
    float*  X      = (float*)w;  w += NN * 32 * 4;
    float*  h3     = (float*)w;  w += NN * 4;

    const int G_E4K = (NE + 4095) / 4096;   // 586
    const int G_N   = (NN + 255) / 256;     // 391

    // build sorted edge structure
    k_zero<<<(NBINP + 255) / 256, 256, 0, stream>>>(cnt);
    k_hist<<<G_E4K, 512, 0, stream>>>(ei, cnt);
    k_scan<<<1, 512, 0, stream>>>(cnt, base, cur);
    k_binscatter<<<G_E4K, 512, 0, stream>>>(ei, cur, binned);
    k_degrees<<<NB, 256, 0, stream>>>(binned, base, dinv);
    k_prescale<<<G_N, 256, 0, stream>>>(x, dinv, xs);

    // layer 1 -> Y (prescaled)
    k_gl1<<<NB, 1024, 0, stream>>>(xs, binned, base, dinv, W1, b1, Y);
    // layer 2 -> X (prescaled)
    k_gl2<<<NB, 1024, 0, stream>>>(Y, binned, base, dinv, W2, b2, X);
    // layer 3
    k_l3t<<<G_N, 256, 0, stream>>>(X, W3, h3);
    k_gl3<<<NB, 1024, 0, stream>>>(h3, binned, base, dinv, b3, out);
}

// Round 5
// 347.464 us; speedup vs baseline: 2.1815x; 2.1815x over previous
//
#include <hip/hip_runtime.h>

#define NN 100000
#define NE 2400000
#define NB 391              // buckets of 256 dst nodes
#define P  7                // src chunks (src>>14, max 99999>>14 = 6)
#define NBIN 2737           // NB*P
#define NBINP 3072          // padded (512*6)

// ---------------- zero bin counters ----------------
__global__ void k_zero(int* __restrict__ c) {
    int i = blockIdx.x * 256 + threadIdx.x;
    if (i < NBINP) c[i] = 0;
}

// ---------------- histogram over (dstBucket, srcChunk) bins ----------------
__global__ __launch_bounds__(512) void k_hist(const int* __restrict__ ei,
                                              int* __restrict__ cnt) {
    __shared__ int hist[NBINP];
    int tid = threadIdx.x;
    for (int i = tid; i < NBINP; i += 512) hist[i] = 0;
    __syncthreads();
    int e0 = blockIdx.x * 4096;
    for (int k = 0; k < 8; ++k) {
        int e = e0 + k * 512 + tid;
        if (e < NE) {
            int s = ei[e], d = ei[NE + e];
            atomicAdd(&hist[(d >> 8) * P + (s >> 14)], 1);
        }
    }
    __syncthreads();
    for (int i = tid; i < NBIN; i += 512)
        if (hist[i]) atomicAdd(&cnt[i], hist[i]);
}

// ---------------- exclusive scan over bins (1 block) ----------------
__global__ __launch_bounds__(512) void k_scan(const int* __restrict__ cnt,
        int* __restrict__ base, int* __restrict__ cur, int* __restrict__ rs) {
    __shared__ int sh[512];
    int tid = threadIdx.x;
    int loc[6]; int s = 0; int b6 = tid * 6;
    for (int j = 0; j < 6; ++j) { int v = cnt[b6 + j]; loc[j] = s; s += v; }
    sh[tid] = s; __syncthreads();
    for (int off = 1; off < 512; off <<= 1) {
        int t = (tid >= off) ? sh[tid - off] : 0; __syncthreads();
        sh[tid] += t; __syncthreads();
    }
    int excl = sh[tid] - s;
    for (int j = 0; j < 6; ++j) {
        int v = excl + loc[j];
        base[b6 + j] = v;          // zero-count bins: base == NE
        cur[b6 + j] = v;
    }
    if (tid == 0) rs[NN] = NE;
}

// ---------------- bin edges by (bucket,srcchunk), LDS-grouped writes ----------------
__global__ __launch_bounds__(512) void k_binscatter(const int* __restrict__ ei,
        int* __restrict__ cur, int* __restrict__ binned) {
    __shared__ int hist[NBINP], lbase[NBINP], myb[NBINP];
    __shared__ int sh[512];
    __shared__ int stage[4096];
    __shared__ unsigned short stageb[4096];
    int tid = threadIdx.x;
    for (int i = tid; i < NBINP; i += 512) hist[i] = 0;
    __syncthreads();
    int e0 = blockIdx.x * 4096;
    int pk[8], bn[8];
    for (int k = 0; k < 8; ++k) {
        int e = e0 + k * 512 + tid;
        if (e < NE) {
            int s = ei[e], d = ei[NE + e];
            bn[k] = (d >> 8) * P + (s >> 14);
            pk[k] = s | ((d & 255) << 17);
            atomicAdd(&hist[bn[k]], 1);
        } else bn[k] = -1;
    }
    __syncthreads();
    int loc[6]; int s = 0; int b6 = tid * 6;
    for (int j = 0; j < 6; ++j) { int v = hist[b6 + j]; loc[j] = s; s += v; }
    sh[tid] = s; __syncthreads();
    for (int off = 1; off < 512; off <<= 1) {
        int t = (tid >= off) ? sh[tid - off] : 0; __syncthreads();
        sh[tid] += t; __syncthreads();
    }
    int excl = sh[tid] - s;
    int T = sh[511];
    for (int j = 0; j < 6; ++j) lbase[b6 + j] = excl + loc[j];
    __syncthreads();
    for (int i = tid; i < NBIN; i += 512) {
        int v = hist[i];
        if (v > 0) myb[i] = atomicAdd(&cur[i], v);
    }
    __syncthreads();
    for (int i = tid; i < NBINP; i += 512) hist[i] = 0;
    __syncthreads();
    for (int k = 0; k < 8; ++k) {
        if (bn[k] >= 0) {
            int r = atomicAdd(&hist[bn[k]], 1);
            int slot = lbase[bn[k]] + r;
            stage[slot] = pk[k];
            stageb[slot] = (unsigned short)bn[k];
        }
    }
    __syncthreads();
    for (int j = tid; j < T; j += 512) {
        int b = stageb[j];
        binned[myb[b] + (j - lbase[b])] = stage[j];
    }
}

// ---------------- per-bucket chunk-ordered CSR + rs + dinv ----------------
__global__ __launch_bounds__(256) void k_local_csr(const int* __restrict__ binned,
        const int* __restrict__ base, int* __restrict__ rs,
        float* __restrict__ dinv, int* __restrict__ csr) {
    __shared__ int cnt[256 * P], cur[256 * P];
    __shared__ int sh[256];
    int tid = threadIdx.x, b = blockIdx.x;
    int e0 = base[b * P];
    for (int i = tid; i < 256 * P; i += 256) cnt[i] = 0;
    __syncthreads();
    for (int c = 0; c < P; ++c) {
        int s = base[b * P + c], e = base[b * P + c + 1];
        for (int j = s + tid; j < e; j += 256)
            atomicAdd(&cnt[((binned[j] >> 17) & 255) * P + c], 1);
    }
    __syncthreads();
    int t = 0, loc[P];
    for (int c = 0; c < P; ++c) { loc[c] = t; t += cnt[tid * P + c]; }
    sh[tid] = t; __syncthreads();
    for (int off = 1; off < 256; off <<= 1) {
        int v = (tid >= off) ? sh[tid - off] : 0; __syncthreads();
        sh[tid] += v; __syncthreads();
    }
    int nb = sh[tid] - t;                       // node base within bucket
    int node = (b << 8) + tid;
    if (node < NN) { dinv[node] = rsqrtf((float)(t + 1)); rs[node] = e0 + nb; }
    for (int c = 0; c < P; ++c) cur[tid * P + c] = nb + loc[c];
    __syncthreads();
    for (int c = 0; c < P; ++c) {
        int s = base[b * P + c], e = base[b * P + c + 1];
        for (int j = s + tid; j < e; j += 256) {
            int w = binned[j];
            int ln = (w >> 17) & 255;
            int p = atomicAdd(&cur[ln * P + c], 1);
            csr[e0 + p] = w & 0x1FFFF;          // chunk-ordered per node
        }
    }
}

// ---------------- prescale x by dinv ----------------
__global__ void k_prescale(const float* __restrict__ x, const float* __restrict__ dinv,
                           float2* __restrict__ xs) {
    int i = blockIdx.x * 256 + threadIdx.x;
    if (i < NN) {
        float2 v = ((const float2*)x)[i];
        float di = dinv[i];
        xs[i] = make_float2(di * v.x, di * v.y);
    }
}

// ---------------- layer 1: node-parallel 2-wide gather + W1 epilogue ----------------
__global__ __launch_bounds__(256) void k_gather_l1(const float2* __restrict__ xs,
        const int* __restrict__ csr, const int* __restrict__ rs,
        const float* __restrict__ dinv, const float* __restrict__ W,
        const float* __restrict__ bias, float* __restrict__ Y) {
    int node = blockIdx.x * 8 + (threadIdx.x >> 5);
    int f = threadIdx.x & 31;
    if (node >= NN) return;
    int beg = rs[node], end = rs[node + 1];
    float2 xn = xs[node];
    float sx = xn.x, sy = xn.y;                 // self-loop (prescaled)
    int e = beg;
    for (; e + 4 <= end; e += 4) {
        int s0 = csr[e], s1 = csr[e + 1], s2 = csr[e + 2], s3 = csr[e + 3];
        float2 a = xs[s0], b2 = xs[s1], c = xs[s2], d = xs[s3];
        sx += a.x + b2.x + c.x + d.x;
        sy += a.y + b2.y + c.y + d.y;
    }
    for (; e < end; ++e) { float2 a = xs[csr[e]]; sx += a.x; sy += a.y; }
    float di = dinv[node];
    float v = di * sx * W[f] + di * sy * W[32 + f] + bias[f];
    Y[(node << 5) + f] = v > 0.f ? v : 0.f;
}

// ---------------- dense 32x32 transform, prescaled output ----------------
__global__ void k_l2t(const float* __restrict__ in, const float* __restrict__ W,
                      const float* __restrict__ dinv, float* __restrict__ h) {
    __shared__ float Ws[32 * 32];
    for (int j = threadIdx.x; j < 1024; j += blockDim.x) Ws[j] = W[j];
    __syncthreads();
    int t = blockIdx.x * blockDim.x + threadIdx.x;
    if (t >= NN * 32) return;
    int i = t >> 5, f = t & 31;
    const float* row = in + i * 32;
    float v = 0.f;
#pragma unroll
    for (int k = 0; k < 32; ++k) v += row[k] * Ws[k * 32 + f];
    h[t] = dinv[i] * v;                         // prescaled by dinv[src]
}

// ---------------- width-32 gather (prescaled table) + bias + relu ----------------
__global__ __launch_bounds__(256) void k_gather32(const float* __restrict__ hs,
        const int* __restrict__ csr, const int* __restrict__ rs,
        const float* __restrict__ dinv, const float* __restrict__ bias,
        float* __restrict__ out) {
    int node = blockIdx.x * 8 + (threadIdx.x >> 5);
    int f = threadIdx.x & 31;
    if (node >= NN) return;
    int beg = rs[node], end = rs[node + 1];
    float acc = hs[(node << 5) + f];            // self-loop
    int e = beg;
    for (; e + 4 <= end; e += 4) {
        int s0 = csr[e], s1 = csr[e + 1], s2 = csr[e + 2], s3 = csr[e + 3];
        float v0 = hs[(s0 << 5) + f], v1 = hs[(s1 << 5) + f];
        float v2 = hs[(s2 << 5) + f], v3 = hs[(s3 << 5) + f];
        acc += (v0 + v1) + (v2 + v3);
    }
    for (; e < end; ++e) acc += hs[(csr[e] << 5) + f];
    float v = dinv[node] * acc + bias[f];
    out[(node << 5) + f] = v > 0.f ? v : 0.f;
}

// ---------------- layer 3 transform (32->1), prescaled ----------------
__global__ void k_l3t(const float* __restrict__ in, const float* __restrict__ W,
                      const float* __restrict__ dinv, float* __restrict__ h) {
    int i = blockIdx.x * 256 + threadIdx.x;
    if (i >= NN) return;
    const float4* row = (const float4*)(in + i * 32);
    const float4* w4 = (const float4*)W;
    float v = 0.f;
#pragma unroll
    for (int k = 0; k < 8; ++k) {
        float4 r = row[k], w = w4[k];
        v += r.x * w.x + r.y * w.y + r.z * w.z + r.w * w.w;
    }
    h[i] = dinv[i] * v;
}

// ---------------- width-1 gather -> out ----------------
__global__ __launch_bounds__(256) void k_gather_out(const float* __restrict__ hs,
        const int* __restrict__ csr, const int* __restrict__ rs,
        const float* __restrict__ dinv, const float* __restrict__ bias,
        float* __restrict__ out) {
    int node = blockIdx.x * 256 + threadIdx.x;
    if (node >= NN) return;
    int beg = rs[node], end = rs[node + 1];
    float acc = hs[node];
    int e = beg;
    for (; e + 4 <= end; e += 4) {
        int s0 = csr[e], s1 = csr[e + 1], s2 = csr[e + 2], s3 = csr[e + 3];
        acc += (hs[s0] + hs[s1]) + (hs[s2] + hs[s3]);
    }
    for (; e < end; ++e) acc += hs[csr[e]];
    out[node] = dinv[node] * acc + bias[0];
}

extern "C" void kernel_launch(void* const* d_in, const int* in_sizes, int n_in,
                              void* d_out, int out_size, void* d_ws, size_t ws_size,
                              hipStream_t stream) {
    const float* x  = (const float*)d_in[0];
    const int*   ei = (const int*)d_in[1];   // [2, NE] int32
    const float* W1 = (const float*)d_in[2];
    const float* b1 = (const float*)d_in[3];
    const float* W2 = (const float*)d_in[4];
    const float* b2 = (const float*)d_in[5];
    const float* W3 = (const float*)d_in[6];
    const float* b3 = (const float*)d_in[7];
    float* out = (float*)d_out;

    char* w = (char*)d_ws;
    float2* xs   = (float2*)w;  w += NN * 8;            // 8B-aligned first
    int*   cnt   = (int*)w;     w += NBINP * 4;
    int*   base  = (int*)w;     w += (NBINP + 1) * 4;
    int*   cur   = (int*)w;     w += NBINP * 4;
    int*   rs    = (int*)w;     w += (NN + 1) * 4;
    float* dinv  = (float*)w;   w += NN * 4;
    int*   csr   = (int*)w;     w += NE * 4;
    float* X     = (float*)w;   w += NN * 32 * 4;       // 12.8 MB
    float* Y     = (float*)w;   w += NN * 32 * 4;       // 12.8 MB
    float* h3    = (float*)w;   w += NN * 4;
    int*   binned = (int*)X;    // dead before X is first written (k_l2t)

    const int G_E4K = (NE + 4095) / 4096;   // 586
    const int G_N   = (NN + 255) / 256;     // 391
    const int G_G   = (NN + 7) / 8;         // 12500
    const int G_N32 = (NN * 32 + 255) / 256;

    // build chunk-sorted CSR
    k_zero<<<(NBINP + 255) / 256, 256, 0, stream>>>(cnt);
    k_hist<<<G_E4K, 512, 0, stream>>>(ei, cnt);
    k_scan<<<1, 512, 0, stream>>>(cnt, base, cur, rs);
    k_binscatter<<<G_E4K, 512, 0, stream>>>(ei, cur, binned);
    k_local_csr<<<NB, 256, 0, stream>>>(binned, base, rs, dinv, csr);
    k_prescale<<<G_N, 256, 0, stream>>>(x, dinv, xs);

    // layer 1 -> Y
    k_gather_l1<<<G_G, 256, 0, stream>>>(xs, csr, rs, dinv, W1, b1, Y);
    // layer 2: Y -> X (prescaled h), gather -> Y
    k_l2t<<<G_N32, 256, 0, stream>>>(Y, W2, dinv, X);
    k_gather32<<<G_G, 256, 0, stream>>>(X, csr, rs, dinv, b2, Y);
    // layer 3: Y -> h3 (prescaled), gather -> out
    k_l3t<<<G_N, 256, 0, stream>>>(Y, W3, dinv, h3);
    k_gather_out<<<G_N, 256, 0, stream>>>(h3, csr, rs, dinv, b3, out);
}

// Round 6
// 266.360 us; speedup vs baseline: 2.8457x; 1.3045x over previous
//
#include <hip/hip_runtime.h>

#define NN 100000
#define NE 2400000
#define NB 391              // buckets of 256 dst nodes

// ---------------- zero bin counters ----------------
__global__ void k_zero(int* __restrict__ c) {
    int i = blockIdx.x * 256 + threadIdx.x;
    if (i < NB + 1) c[i] = 0;
}

// ---------------- bucket histogram (dst only) ----------------
__global__ __launch_bounds__(512) void k_hist(const int* __restrict__ ei,
                                              int* __restrict__ cnt) {
    __shared__ int hist[NB];
    int tid = threadIdx.x;
    for (int i = tid; i < NB; i += 512) hist[i] = 0;
    __syncthreads();
    int e0 = blockIdx.x * 4096;
    for (int k = 0; k < 8; ++k) {
        int e = e0 + k * 512 + tid;
        if (e < NE) atomicAdd(&hist[ei[NE + e] >> 8], 1);
    }
    __syncthreads();
    for (int i = tid; i < NB; i += 512)
        if (hist[i]) atomicAdd(&cnt[i], hist[i]);
}

// ---------------- exclusive scan over buckets ----------------
__global__ __launch_bounds__(512) void k_scan(const int* __restrict__ cnt,
        int* __restrict__ base, int* __restrict__ cur, int* __restrict__ rs) {
    __shared__ int sh[512];
    int tid = threadIdx.x;
    int v = (tid < NB) ? cnt[tid] : 0;
    sh[tid] = v; __syncthreads();
    for (int off = 1; off < 512; off <<= 1) {
        int t = (tid >= off) ? sh[tid - off] : 0; __syncthreads();
        sh[tid] += t; __syncthreads();
    }
    int excl = sh[tid] - v;
    if (tid <= NB) base[tid] = excl;   // base[NB] = NE
    if (tid < NB) cur[tid] = excl;
    if (tid == 0) rs[NN] = NE;
}

// ---------------- bin edges by dst-bucket, LDS-grouped writes ----------------
__global__ __launch_bounds__(512) void k_binscatter(const int* __restrict__ ei,
        int* __restrict__ cur, int* __restrict__ binned) {
    __shared__ int hist[NB], lbase[NB], myb[NB];
    __shared__ int sh[512];
    __shared__ int stage[4096];
    __shared__ unsigned short stageb[4096];
    __shared__ int tot;
    int tid = threadIdx.x;
    for (int i = tid; i < NB; i += 512) hist[i] = 0;
    __syncthreads();
    int e0 = blockIdx.x * 4096;
    int pk[8], bn[8];
    for (int k = 0; k < 8; ++k) {
        int e = e0 + k * 512 + tid;
        if (e < NE) {
            int s = ei[e], d = ei[NE + e];
            bn[k] = d >> 8;
            pk[k] = s | ((d & 255) << 17);
            atomicAdd(&hist[bn[k]], 1);
        } else bn[k] = -1;
    }
    __syncthreads();
    int v = (tid < NB) ? hist[tid] : 0;
    sh[tid] = v; __syncthreads();
    for (int off = 1; off < 512; off <<= 1) {
        int t = (tid >= off) ? sh[tid - off] : 0; __syncthreads();
        sh[tid] += t; __syncthreads();
    }
    if (tid < NB) lbase[tid] = sh[tid] - v;
    if (tid == 511) tot = sh[511];
    if (tid < NB && v > 0) myb[tid] = atomicAdd(&cur[tid], v);
    __syncthreads();
    sh[tid] = 0;
    if (tid < NB) hist[tid] = 0;
    __syncthreads();
    for (int k = 0; k < 8; ++k) {
        if (bn[k] >= 0) {
            int r = atomicAdd(&hist[bn[k]], 1);
            int slot = lbase[bn[k]] + r;
            stage[slot] = pk[k];
            stageb[slot] = (unsigned short)bn[k];
        }
    }
    __syncthreads();
    int T = tot;
    for (int j = tid; j < T; j += 512) {
        int b = stageb[j];
        binned[myb[b] + (j - lbase[b])] = stage[j];
    }
}

// ---------------- per-bucket degree count -> rs, dinv, prescaled xs ----------------
__global__ __launch_bounds__(256) void k_csr_count(const int* __restrict__ binned,
        const int* __restrict__ base, const float* __restrict__ x,
        int* __restrict__ rs, float* __restrict__ dinv, float2* __restrict__ xs) {
    __shared__ int cnt[256], sh[256];
    int tid = threadIdx.x, b = blockIdx.x;
    int e0 = base[b], e1 = base[b + 1];
    cnt[tid] = 0;
    __syncthreads();
    for (int j = e0 + tid; j < e1; j += 256)
        atomicAdd(&cnt[(binned[j] >> 17) & 255], 1);
    __syncthreads();
    int v = cnt[tid];
    sh[tid] = v; __syncthreads();
    for (int off = 1; off < 256; off <<= 1) {
        int t = (tid >= off) ? sh[tid - off] : 0; __syncthreads();
        sh[tid] += t; __syncthreads();
    }
    int node = (b << 8) + tid;
    if (node < NN) {
        rs[node] = e0 + sh[tid] - v;
        float di = rsqrtf((float)(v + 1));     // +1 self-loop
        dinv[node] = di;
        float2 xv = ((const float2*)x)[node];
        xs[node] = make_float2(di * xv.x, di * xv.y);
    }
}

// ---------------- csr placement + FUSED layer-1 gather + W1 epilogue ----------------
__global__ __launch_bounds__(256) void k_csr_place(const int* __restrict__ binned,
        const int* __restrict__ base, const int* __restrict__ rs,
        const float2* __restrict__ xs, const float* __restrict__ dinv,
        const float* __restrict__ W, const float* __restrict__ bias,
        int* __restrict__ csr, float* __restrict__ Y) {
    __shared__ int cur[256];
    __shared__ float accx[256], accy[256];
    int tid = threadIdx.x, b = blockIdx.x;
    int e0 = base[b], e1 = base[b + 1];
    int node = (b << 8) + tid;
    cur[tid] = (node < NN) ? (rs[node] - e0) : 0;
    accx[tid] = 0.f; accy[tid] = 0.f;
    __syncthreads();
    for (int j = e0 + tid; j < e1; j += 256) {
        int w = binned[j];
        int s = w & 0x1FFFF, dl = (w >> 17) & 255;
        int p = atomicAdd(&cur[dl], 1);
        csr[e0 + p] = s;
        float2 xv = xs[s];                    // dinv[s]-prescaled
        atomicAdd(&accx[dl], xv.x);
        atomicAdd(&accy[dl], xv.y);
    }
    __syncthreads();
    if (node < NN) {
        float di = dinv[node];
        float2 xn = xs[node];                 // self-loop term
        float a0 = di * (accx[tid] + xn.x);
        float a1 = di * (accy[tid] + xn.y);
        const float4* W4 = (const float4*)W;
        const float4* B4 = (const float4*)bias;
        float4* yrow = (float4*)(Y + (node << 5));
#pragma unroll
        for (int q = 0; q < 8; ++q) {
            float4 w0 = W4[q], w1 = W4[8 + q], bb = B4[q];
            float4 r;
            r.x = a0 * w0.x + a1 * w1.x + bb.x;
            r.y = a0 * w0.y + a1 * w1.y + bb.y;
            r.z = a0 * w0.z + a1 * w1.z + bb.z;
            r.w = a0 * w0.w + a1 * w1.w + bb.w;
            r.x = di * (r.x > 0.f ? r.x : 0.f);
            r.y = di * (r.y > 0.f ? r.y : 0.f);
            r.z = di * (r.z > 0.f ? r.z : 0.f);
            r.w = di * (r.w > 0.f ? r.w : 0.f);
            yrow[q] = r;                      // Y = dinv * relu(...), prescaled
        }
    }
}

// ---------------- width-32 gather + FUSED W2 epilogue ----------------
__global__ __launch_bounds__(256) void k_gather32f(const float* __restrict__ Ys,
        const int* __restrict__ csr, const int* __restrict__ rs,
        const float* __restrict__ dinv, const float* __restrict__ W,
        const float* __restrict__ bias, float* __restrict__ X) {
    __shared__ float accS[256];               // 8 nodes x 32
    __shared__ float Ws[1024];
    for (int j = threadIdx.x; j < 1024; j += 256) Ws[j] = W[j];
    int node = blockIdx.x * 8 + (threadIdx.x >> 5);
    int f = threadIdx.x & 31;
    float acc = 0.f, di = 0.f;
    if (node < NN) {
        int beg = rs[node], end = rs[node + 1];
        acc = Ys[(node << 5) + f];            // self-loop (prescaled)
        int e = beg;
        for (; e + 4 <= end; e += 4) {
            int s0 = csr[e], s1 = csr[e + 1], s2 = csr[e + 2], s3 = csr[e + 3];
            float v0 = Ys[(s0 << 5) + f], v1 = Ys[(s1 << 5) + f];
            float v2 = Ys[(s2 << 5) + f], v3 = Ys[(s3 << 5) + f];
            acc += (v0 + v1) + (v2 + v3);
        }
        for (; e < end; ++e) acc += Ys[(csr[e] << 5) + f];
        di = dinv[node];
    }
    accS[threadIdx.x] = di * acc;             // agg2 = di * (sum + self)
    __syncthreads();                          // also covers Ws
    if (node < NN) {
        int n = threadIdx.x >> 5;
        float sum = bias[f];
#pragma unroll
        for (int k = 0; k < 32; ++k) sum += accS[(n << 5) + k] * Ws[(k << 5) + f];
        X[(node << 5) + f] = di * (sum > 0.f ? sum : 0.f);   // prescaled
    }
}

// ---------------- layer 3 transform (32->1) on prescaled X ----------------
__global__ void k_l3t(const float* __restrict__ in, const float* __restrict__ W,
                      float* __restrict__ h) {
    int i = blockIdx.x * 256 + threadIdx.x;
    if (i >= NN) return;
    const float4* row = (const float4*)(in + i * 32);
    const float4* w4 = (const float4*)W;
    float v = 0.f;
#pragma unroll
    for (int k = 0; k < 8; ++k) {
        float4 r = row[k], w = w4[k];
        v += r.x * w.x + r.y * w.y + r.z * w.z + r.w * w.w;
    }
    h[i] = v;                                 // already dinv-prescaled via X
}

// ---------------- width-1 gather -> out ----------------
__global__ __launch_bounds__(256) void k_gather_out(const float* __restrict__ hs,
        const int* __restrict__ csr, const int* __restrict__ rs,
        const float* __restrict__ dinv, const float* __restrict__ bias,
        float* __restrict__ out) {
    int node = blockIdx.x * 256 + threadIdx.x;
    if (node >= NN) return;
    int beg = rs[node], end = rs[node + 1];
    float acc = hs[node];
    int e = beg;
    for (; e + 4 <= end; e += 4) {
        int s0 = csr[e], s1 = csr[e + 1], s2 = csr[e + 2], s3 = csr[e + 3];
        acc += (hs[s0] + hs[s1]) + (hs[s2] + hs[s3]);
    }
    for (; e < end; ++e) acc += hs[csr[e]];
    out[node] = dinv[node] * acc + bias[0];
}

extern "C" void kernel_launch(void* const* d_in, const int* in_sizes, int n_in,
                              void* d_out, int out_size, void* d_ws, size_t ws_size,
                              hipStream_t stream) {
    const float* x  = (const float*)d_in[0];
    const int*   ei = (const int*)d_in[1];   // [2, NE] int32
    const float* W1 = (const float*)d_in[2];
    const float* b1 = (const float*)d_in[3];
    const float* W2 = (const float*)d_in[4];
    const float* b2 = (const float*)d_in[5];
    const float* W3 = (const float*)d_in[6];
    const float* b3 = (const float*)d_in[7];
    float* out = (float*)d_out;

    char* w = (char*)d_ws;
    float2* xs   = (float2*)w;  w += NN * 8;            // 8B-aligned first
    int*   cnt   = (int*)w;     w += (NB + 1) * 4;
    int*   base  = (int*)w;     w += (NB + 1) * 4;
    int*   cur   = (int*)w;     w += (NB + 1) * 4;
    int*   rs    = (int*)w;     w += (NN + 1) * 4;
    float* dinv  = (float*)w;   w += NN * 4;
    int*   csr   = (int*)w;     w += NE * 4;
    float* X     = (float*)w;   w += NN * 32 * 4;       // 12.8 MB
    float* Y     = (float*)w;   w += NN * 32 * 4;       // 12.8 MB
    float* h3    = (float*)w;   w += NN * 4;
    int*   binned = (int*)X;    // binned dead before X first written (k_gather32f)

    const int G_E4K = (NE + 4095) / 4096;   // 586
    const int G_N   = (NN + 255) / 256;     // 391
    const int G_G   = (NN + 7) / 8;         // 12500

    // build CSR + fused layer 1
    k_zero<<<2, 256, 0, stream>>>(cnt);
    k_hist<<<G_E4K, 512, 0, stream>>>(ei, cnt);
    k_scan<<<1, 512, 0, stream>>>(cnt, base, cur, rs);
    k_binscatter<<<G_E4K, 512, 0, stream>>>(ei, cur, binned);
    k_csr_count<<<NB, 256, 0, stream>>>(binned, base, x, rs, dinv, xs);
    k_csr_place<<<NB, 256, 0, stream>>>(binned, base, rs, xs, dinv, W1, b1, csr, Y);

    // layer 2 (gather + W2 fused) -> X
    k_gather32f<<<G_G, 256, 0, stream>>>(Y, csr, rs, dinv, W2, b2, X);
    // layer 3
    k_l3t<<<G_N, 256, 0, stream>>>(X, W3, h3);
    k_gather_out<<<G_N, 256, 0, stream>>>(h3, csr, rs, dinv, b3, out);
}